// Round 12
// baseline (115.053 us; speedup 1.0000x reference)
//
#include <hip/hip_runtime.h>

// GrCNetConvOnly — R12 DIAGNOSTIC ROUND.
// R8/R10/R11 plateau at ~45us; four structural theories all flat; warm-replay counters
// have never been visible (harness poison fills at ~92us dominate top-5, and rocprof's
// top-5 is duration-sorted). This kernel repeats the full R11 body REPS=3 times in ONE
// dispatch (~135us > fills) so the warm counters finally surface. Work and output are
// identical每 rep -> deterministic, passes re-validation. Decision tree on VALUBusy:
// (a) >=60% issue-bound -> shrink instruction count; (b) 25-40% stall-bound -> MLP/waitcnt;
// (c) low + high mem pressure -> kill cp-split duplicate gathers.

typedef _Float16 h2 __attribute__((ext_vector_type(2)));
typedef _Float16 h8 __attribute__((ext_vector_type(8)));

constexpr int D    = 400;
constexpr int CP   = 25;     // real channel pairs
constexpr int DPAD = 404;    // 4 zeroed pad entries per row: inactive lanes read 0
constexpr int REPS = 3;

static __device__ __forceinline__ float dot2acc(h2 a, h2 b, float c) {
#if __has_builtin(__builtin_amdgcn_fdot2)
    return __builtin_amdgcn_fdot2(a, b, c, false);
#else
    h2 p = a * b; return c + (float)p[0] + (float)p[1];
#endif
}
static __device__ __forceinline__ h2 dup(float v) {
    _Float16 x = (_Float16)v; h2 r; r[0] = x; r[1] = x; return r;
}

__global__ __attribute__((amdgpu_flat_work_group_size(512, 512), amdgpu_waves_per_eu(2, 4)))
void grcnet_pk16h(
    const float* __restrict__ entity_emb,
    const float* __restrict__ relation_emb,
    const float* __restrict__ conv_w,       // (C,1,1,3)
    const float* __restrict__ conv_b,       // (C)
    const float* __restrict__ fc_w,         // (C*D) c-major
    const float* __restrict__ fc_b,         // (1)
    const int*   __restrict__ batch_inputs, // (B,3)
    float* __restrict__ out,                // (B)
    int nB)
{
    __shared__ h2    fc_lds[CP + 1][DPAD];  // 42016 B; row 25 = zeros (dummy cp)
    __shared__ h2    conv_lds[CP + 1][4];   // row 25 mirrors row 24 (harmless)
    __shared__ float partials[2][2][4][4];  // [g][hc][grp][b]

    const int tid  = threadIdx.x;
    const int lane = tid & 63;
    const int wv   = tid >> 6;              // 0..7
    const int grp  = wv >> 1;               // b-group 0..3
    const int hc   = wv & 1;                // cp-half 0..1
    const int bq   = blockIdx.x * 32;       // 32 b per block
    if (bq >= nB) return;

    const float *p0h, *p0r, *p0t, *p1h, *p1r, *p1t;
    const float *p2h, *p2r, *p2t, *p3h, *p3r, *p3t;

    #define SETPTRS(B0)                                                           \
    {                                                                             \
        const int bbase = __builtin_amdgcn_readfirstlane((B0) + 4 * grp);         \
        const int* bi = batch_inputs + 3 * bbase;                                 \
        p0h = entity_emb   + (size_t)bi[0]  * D + lane;                           \
        p0r = relation_emb + (size_t)bi[1]  * D + lane;                           \
        p0t = entity_emb   + (size_t)bi[2]  * D + lane;                           \
        p1h = entity_emb   + (size_t)bi[3]  * D + lane;                           \
        p1r = relation_emb + (size_t)bi[4]  * D + lane;                           \
        p1t = entity_emb   + (size_t)bi[5]  * D + lane;                           \
        p2h = entity_emb   + (size_t)bi[6]  * D + lane;                           \
        p2r = relation_emb + (size_t)bi[7]  * D + lane;                           \
        p2t = entity_emb   + (size_t)bi[8]  * D + lane;                           \
        p3h = entity_emb   + (size_t)bi[9]  * D + lane;                           \
        p3r = relation_emb + (size_t)bi[10] * D + lane;                           \
        p3t = entity_emb   + (size_t)bi[11] * D + lane;                           \
    }

    #define LOADI(S, IDX)                                                         \
        f##S##_0h = p0h[IDX]; f##S##_0r = p0r[IDX]; f##S##_0t = p0t[IDX];         \
        f##S##_1h = p1h[IDX]; f##S##_1r = p1r[IDX]; f##S##_1t = p1t[IDX];         \
        f##S##_2h = p2h[IDX]; f##S##_2r = p2r[IDX]; f##S##_2t = p2t[IDX];         \
        f##S##_3h = p3h[IDX]; f##S##_3r = p3r[IDX]; f##S##_3t = p3t[IDX];

    float fA_0h, fA_0r, fA_0t, fA_1h, fA_1r, fA_1t;
    float fA_2h, fA_2r, fA_2t, fA_3h, fA_3r, fA_3t;
    float fB_0h, fB_0r, fB_0t, fB_1h, fB_1r, fB_1t;
    float fB_2h, fB_2r, fB_2t, fB_3h, fB_3r, fB_3t;

    const h2 zero2 = (h2)(_Float16)0;

    #pragma unroll 1
    for (int rep = 0; rep < REPS; ++rep) {

        // ---- stage fc_w: float4 x2 -> one b128 ds_write ----
        for (int k = tid; k < CP * 100; k += 512) {
            const int cp = k / 100;
            const int dq = k - cp * 100;
            const float4 A  = *(const float4*)(fc_w + (2*cp)     * D + 4*dq);
            const float4 Bv = *(const float4*)(fc_w + (2*cp + 1) * D + 4*dq);
            h8 g;
            g[0]=(_Float16)A.x; g[1]=(_Float16)Bv.x;
            g[2]=(_Float16)A.y; g[3]=(_Float16)Bv.y;
            g[4]=(_Float16)A.z; g[5]=(_Float16)Bv.z;
            g[6]=(_Float16)A.w; g[7]=(_Float16)Bv.w;
            *(h8*)&fc_lds[cp][4*dq] = g;
        }
        {
            h2 z; z[0] = (_Float16)0; z[1] = (_Float16)0;
            if (tid < CP * 4) fc_lds[tid >> 2][D + (tid & 3)] = z;      // pad d=400..403
            if (tid >= 64 && tid < 64 + DPAD) fc_lds[CP][tid - 64] = z; // dummy row = 0
        }
        if (tid < CP + 1) {
            const int src = (tid == CP) ? (CP - 1) : tid;
            const int c0 = 2 * src;
            h2 wa, wb, wc, cb;
            wa[0]=(_Float16)conv_w[3*c0+0]; wa[1]=(_Float16)conv_w[3*c0+3];
            wb[0]=(_Float16)conv_w[3*c0+1]; wb[1]=(_Float16)conv_w[3*c0+4];
            wc[0]=(_Float16)conv_w[3*c0+2]; wc[1]=(_Float16)conv_w[3*c0+5];
            cb[0]=(_Float16)conv_b[c0];     cb[1]=(_Float16)conv_b[c0+1];
            conv_lds[tid][0]=wa; conv_lds[tid][1]=wb;
            conv_lds[tid][2]=wc; conv_lds[tid][3]=cb;
        }
        __syncthreads();

        // ---- unified c-range: hc=0 -> cps 0..12; hc=1 -> cps 13..24 + dummy ----
        const int C0 = 13 * hc;
        constexpr int NC = 13;
        h2 cwa[NC], cwb[NC], cwc[NC], ccb[NC];
        #pragma unroll
        for (int j = 0; j < NC; ++j) {
            cwa[j] = conv_lds[C0+j][0]; cwb[j] = conv_lds[C0+j][1];
            cwc[j] = conv_lds[C0+j][2]; ccb[j] = conv_lds[C0+j][3];
        }

        const int  d6 = lane + 384;
        const bool a6 = (d6 < D);
        const int  i6 = a6 ? 384 : -lane;        // p[i6] == row[clamped d]
        const h2* fcb  = &fc_lds[0][0] + C0 * DPAD + lane;
        const h2* fcb6 = &fc_lds[0][0] + C0 * DPAD + (a6 ? d6 : D);

        #define COMPUTE(S, FB, FIDX0)                                             \
        {                                                                         \
            const h2 H0=dup(f##S##_0h), R0=dup(f##S##_0r), T0=dup(f##S##_0t);     \
            const h2 H1=dup(f##S##_1h), R1=dup(f##S##_1r), T1=dup(f##S##_1t);     \
            const h2 H2=dup(f##S##_2h), R2=dup(f##S##_2r), T2=dup(f##S##_2t);     \
            const h2 H3=dup(f##S##_3h), R3=dup(f##S##_3r), T3=dup(f##S##_3t);     \
            _Pragma("unroll")                                                     \
            for (int j = 0; j < NC; ++j) {                                        \
                const h2 f2 = (FB)[(FIDX0) + j * DPAD];      /* imm offset */     \
                h2 s0 = H0*cwa[j] + (R0*cwb[j] + (T0*cwc[j] + ccb[j]));           \
                h2 s1 = H1*cwa[j] + (R1*cwb[j] + (T1*cwc[j] + ccb[j]));           \
                h2 s2 = H2*cwa[j] + (R2*cwb[j] + (T2*cwc[j] + ccb[j]));           \
                h2 s3 = H3*cwa[j] + (R3*cwb[j] + (T3*cwc[j] + ccb[j]));           \
                s0 = __builtin_elementwise_max(s0, zero2);                        \
                s1 = __builtin_elementwise_max(s1, zero2);                        \
                s2 = __builtin_elementwise_max(s2, zero2);                        \
                s3 = __builtin_elementwise_max(s3, zero2);                        \
                acc0 = dot2acc(s0, f2, acc0);                                     \
                acc1 = dot2acc(s1, f2, acc1);                                     \
                acc2 = dot2acc(s2, f2, acc2);                                     \
                acc3 = dot2acc(s3, f2, acc3);                                     \
            }                                                                     \
        }

        #pragma unroll 1
        for (int g = 0; g < 2; ++g) {
            const int b0 = bq + 16 * g;
            SETPTRS(b0)
            LOADI(A, 0)
            LOADI(B, 64)
            float acc0 = 0.f, acc1 = 0.f, acc2 = 0.f, acc3 = 0.f;

            COMPUTE(A, fcb, 0*64)   LOADI(A, 128)
            COMPUTE(B, fcb, 1*64)   LOADI(B, 192)
            COMPUTE(A, fcb, 2*64)   LOADI(A, 256)
            COMPUTE(B, fcb, 3*64)   LOADI(B, 320)
            COMPUTE(A, fcb, 4*64)   LOADI(A, i6)
            COMPUTE(B, fcb, 5*64)
            COMPUTE(A, fcb6, 0)

            #pragma unroll
            for (int off = 32; off > 0; off >>= 1) {
                acc0 += __shfl_xor(acc0, off);
                acc1 += __shfl_xor(acc1, off);
                acc2 += __shfl_xor(acc2, off);
                acc3 += __shfl_xor(acc3, off);
            }
            if (lane == 0) {
                partials[g][hc][grp][0] = acc0; partials[g][hc][grp][1] = acc1;
                partials[g][hc][grp][2] = acc2; partials[g][hc][grp][3] = acc3;
            }
        }
        #undef COMPUTE

        __syncthreads();

        if (tid < 32) {
            const int g = tid >> 4, idx = tid & 15;
            const int gr = idx >> 2, j = idx & 3;
            const int b = bq + 16 * g + 4 * gr + j;
            if (b < nB)
                out[b] = partials[g][0][gr][j] + partials[g][1][gr][j] + fc_b[0];
        }
        __syncthreads();   // protect partials/fc_lds before next rep re-stages
    }
    #undef LOADI
    #undef SETPTRS
}

extern "C" void kernel_launch(void* const* d_in, const int* in_sizes, int n_in,
                              void* d_out, int out_size, void* d_ws, size_t ws_size,
                              hipStream_t stream) {
    const float* entity_emb   = (const float*)d_in[0];
    const float* relation_emb = (const float*)d_in[1];
    const float* conv_w       = (const float*)d_in[2];
    const float* conv_b       = (const float*)d_in[3];
    const float* fc_w         = (const float*)d_in[4];
    const float* fc_b         = (const float*)d_in[5];
    const int*   batch_inputs = (const int*)d_in[6];
    float* out = (float*)d_out;

    const int nB = in_sizes[6] / 3;          // 16384
    const int blocks = (nB + 31) / 32;       // 512
    grcnet_pk16h<<<blocks, 512, 0, stream>>>(
        entity_emb, relation_emb, conv_w, conv_b, fc_w, fc_b, batch_inputs, out, nB);
}

// Round 13
// 104.467 us; speedup vs baseline: 1.1013x; 1.1013x over previous
//
#include <hip/hip_runtime.h>

// GrCNetConvOnly: out[b] = sum_{c,d} relu(wa[c]*h+wb[c]*r+wc[c]*t+cb[c]) * fcw[c*D+d] + fcb
// B=16384, D=400, C=50.
// R12 diagnostic: VALUBusy 65%, VGPR=116 (-> only 4 waves/SIMD), memory trivial.
// R13: conv coefficient arrays (52 wave-uniform h2 VGPRs) moved to SGPRs via
// readfirstlane; VOP3P pk_fma takes the SGPR directly (1 sgpr/instr rule ok).
// VGPR ~116 -> ~70 => waves_per_eu(6,8) lifts residency to 6-8 waves/SIMD to
// hide the 35% idle. Structure otherwise identical to R11/R12 (proven).

typedef _Float16 h2 __attribute__((ext_vector_type(2)));
typedef _Float16 h8 __attribute__((ext_vector_type(8)));

constexpr int D    = 400;
constexpr int CP   = 25;     // real channel pairs
constexpr int DPAD = 404;    // 4 zeroed pad entries per row: inactive lanes read 0

static __device__ __forceinline__ float dot2acc(h2 a, h2 b, float c) {
#if __has_builtin(__builtin_amdgcn_fdot2)
    return __builtin_amdgcn_fdot2(a, b, c, false);
#else
    h2 p = a * b; return c + (float)p[0] + (float)p[1];
#endif
}
static __device__ __forceinline__ h2 dup(float v) {
    _Float16 x = (_Float16)v; h2 r; r[0] = x; r[1] = x; return r;
}
static __device__ __forceinline__ h2 s2h(unsigned u) {
    return __builtin_bit_cast(h2, u);
}

__global__ __attribute__((amdgpu_flat_work_group_size(512, 512), amdgpu_waves_per_eu(6, 8)))
void grcnet_pk16i(
    const float* __restrict__ entity_emb,
    const float* __restrict__ relation_emb,
    const float* __restrict__ conv_w,       // (C,1,1,3)
    const float* __restrict__ conv_b,       // (C)
    const float* __restrict__ fc_w,         // (C*D) c-major
    const float* __restrict__ fc_b,         // (1)
    const int*   __restrict__ batch_inputs, // (B,3)
    float* __restrict__ out,                // (B)
    int nB)
{
    __shared__ h2    fc_lds[CP + 1][DPAD];  // 42016 B; row 25 = zeros (dummy cp)
    __shared__ h2    conv_lds[CP + 1][4];   // row 25 mirrors row 24 (harmless)
    __shared__ float partials[2][2][4][4];  // [g][hc][grp][b]

    const int tid  = threadIdx.x;
    const int lane = tid & 63;
    const int wv   = tid >> 6;              // 0..7
    const int grp  = wv >> 1;               // b-group 0..3
    const int hc   = wv & 1;                // cp-half 0..1
    const int bq   = blockIdx.x * 32;       // 32 b per block
    if (bq >= nB) return;

    const float *p0h, *p0r, *p0t, *p1h, *p1r, *p1t;
    const float *p2h, *p2r, *p2t, *p3h, *p3r, *p3t;

    #define SETPTRS(B0)                                                           \
    {                                                                             \
        const int bbase = __builtin_amdgcn_readfirstlane((B0) + 4 * grp);         \
        const int* bi = batch_inputs + 3 * bbase;                                 \
        p0h = entity_emb   + (size_t)bi[0]  * D + lane;                           \
        p0r = relation_emb + (size_t)bi[1]  * D + lane;                           \
        p0t = entity_emb   + (size_t)bi[2]  * D + lane;                           \
        p1h = entity_emb   + (size_t)bi[3]  * D + lane;                           \
        p1r = relation_emb + (size_t)bi[4]  * D + lane;                           \
        p1t = entity_emb   + (size_t)bi[5]  * D + lane;                           \
        p2h = entity_emb   + (size_t)bi[6]  * D + lane;                           \
        p2r = relation_emb + (size_t)bi[7]  * D + lane;                           \
        p2t = entity_emb   + (size_t)bi[8]  * D + lane;                           \
        p3h = entity_emb   + (size_t)bi[9]  * D + lane;                           \
        p3r = relation_emb + (size_t)bi[10] * D + lane;                           \
        p3t = entity_emb   + (size_t)bi[11] * D + lane;                           \
    }

    #define LOADI(S, IDX)                                                         \
        f##S##_0h = p0h[IDX]; f##S##_0r = p0r[IDX]; f##S##_0t = p0t[IDX];         \
        f##S##_1h = p1h[IDX]; f##S##_1r = p1r[IDX]; f##S##_1t = p1t[IDX];         \
        f##S##_2h = p2h[IDX]; f##S##_2r = p2r[IDX]; f##S##_2t = p2t[IDX];         \
        f##S##_3h = p3h[IDX]; f##S##_3r = p3r[IDX]; f##S##_3t = p3t[IDX];

    float fA_0h, fA_0r, fA_0t, fA_1h, fA_1r, fA_1t;
    float fA_2h, fA_2r, fA_2t, fA_3h, fA_3r, fA_3t;
    float fB_0h, fB_0r, fB_0t, fB_1h, fB_1r, fB_1t;
    float fB_2h, fB_2r, fB_2t, fB_3h, fB_3r, fB_3t;

    const h2 zero2 = (h2)(_Float16)0;

    // ---- stage fc_w: float4 x2 -> one b128 ds_write ----
    for (int k = tid; k < CP * 100; k += 512) {
        const int cp = k / 100;
        const int dq = k - cp * 100;
        const float4 A  = *(const float4*)(fc_w + (2*cp)     * D + 4*dq);
        const float4 Bv = *(const float4*)(fc_w + (2*cp + 1) * D + 4*dq);
        h8 g;
        g[0]=(_Float16)A.x; g[1]=(_Float16)Bv.x;
        g[2]=(_Float16)A.y; g[3]=(_Float16)Bv.y;
        g[4]=(_Float16)A.z; g[5]=(_Float16)Bv.z;
        g[6]=(_Float16)A.w; g[7]=(_Float16)Bv.w;
        *(h8*)&fc_lds[cp][4*dq] = g;
    }
    {
        h2 z; z[0] = (_Float16)0; z[1] = (_Float16)0;
        if (tid < CP * 4) fc_lds[tid >> 2][D + (tid & 3)] = z;      // pad d=400..403
        if (tid >= 64 && tid < 64 + DPAD) fc_lds[CP][tid - 64] = z; // dummy row = 0
    }
    if (tid < CP + 1) {
        const int src = (tid == CP) ? (CP - 1) : tid;
        const int c0 = 2 * src;
        h2 wa, wb, wc, cb;
        wa[0]=(_Float16)conv_w[3*c0+0]; wa[1]=(_Float16)conv_w[3*c0+3];
        wb[0]=(_Float16)conv_w[3*c0+1]; wb[1]=(_Float16)conv_w[3*c0+4];
        wc[0]=(_Float16)conv_w[3*c0+2]; wc[1]=(_Float16)conv_w[3*c0+5];
        cb[0]=(_Float16)conv_b[c0];     cb[1]=(_Float16)conv_b[c0+1];
        conv_lds[tid][0]=wa; conv_lds[tid][1]=wb;
        conv_lds[tid][2]=wc; conv_lds[tid][3]=cb;
    }
    __syncthreads();

    // ---- unified c-range: hc=0 -> cps 0..12; hc=1 -> cps 13..24 + dummy ----
    const int C0 = 13 * hc;
    constexpr int NC = 13;

    // conv coefficients -> SGPRs (wave-uniform; frees ~52 VGPRs).
    // Unrolled constant indices -> named uniform values, no scratch (rule #20 ok).
    unsigned cwa_u[NC], cwb_u[NC], cwc_u[NC], ccb_u[NC];
    #pragma unroll
    for (int j = 0; j < NC; ++j) {
        cwa_u[j] = __builtin_amdgcn_readfirstlane(__builtin_bit_cast(unsigned, conv_lds[C0+j][0]));
        cwb_u[j] = __builtin_amdgcn_readfirstlane(__builtin_bit_cast(unsigned, conv_lds[C0+j][1]));
        cwc_u[j] = __builtin_amdgcn_readfirstlane(__builtin_bit_cast(unsigned, conv_lds[C0+j][2]));
        ccb_u[j] = __builtin_amdgcn_readfirstlane(__builtin_bit_cast(unsigned, conv_lds[C0+j][3]));
    }

    const int  d6 = lane + 384;
    const bool a6 = (d6 < D);
    const int  i6 = a6 ? 384 : -lane;        // p[i6] == row[clamped d]
    const h2* fcb  = &fc_lds[0][0] + C0 * DPAD + lane;
    const h2* fcb6 = &fc_lds[0][0] + C0 * DPAD + (a6 ? d6 : D);

    #define COMPUTE(S, FB, FIDX0)                                                 \
    {                                                                             \
        const h2 H0=dup(f##S##_0h), R0=dup(f##S##_0r), T0=dup(f##S##_0t);         \
        const h2 H1=dup(f##S##_1h), R1=dup(f##S##_1r), T1=dup(f##S##_1t);         \
        const h2 H2=dup(f##S##_2h), R2=dup(f##S##_2r), T2=dup(f##S##_2t);         \
        const h2 H3=dup(f##S##_3h), R3=dup(f##S##_3r), T3=dup(f##S##_3t);         \
        _Pragma("unroll")                                                         \
        for (int j = 0; j < NC; ++j) {                                            \
            const h2 wa = s2h(cwa_u[j]), wb = s2h(cwb_u[j]);                      \
            const h2 wc = s2h(cwc_u[j]), cb = s2h(ccb_u[j]);                      \
            const h2 f2 = (FB)[(FIDX0) + j * DPAD];      /* imm offset */         \
            h2 s0 = H0*wa + (R0*wb + (T0*wc + cb));                               \
            h2 s1 = H1*wa + (R1*wb + (T1*wc + cb));                               \
            h2 s2 = H2*wa + (R2*wb + (T2*wc + cb));                               \
            h2 s3 = H3*wa + (R3*wb + (T3*wc + cb));                               \
            s0 = __builtin_elementwise_max(s0, zero2);                            \
            s1 = __builtin_elementwise_max(s1, zero2);                            \
            s2 = __builtin_elementwise_max(s2, zero2);                            \
            s3 = __builtin_elementwise_max(s3, zero2);                            \
            acc0 = dot2acc(s0, f2, acc0);                                         \
            acc1 = dot2acc(s1, f2, acc1);                                         \
            acc2 = dot2acc(s2, f2, acc2);                                         \
            acc3 = dot2acc(s3, f2, acc3);                                         \
        }                                                                         \
    }

    #pragma unroll 1
    for (int g = 0; g < 2; ++g) {
        const int b0 = bq + 16 * g;
        SETPTRS(b0)
        LOADI(A, 0)
        LOADI(B, 64)
        float acc0 = 0.f, acc1 = 0.f, acc2 = 0.f, acc3 = 0.f;

        COMPUTE(A, fcb, 0*64)   LOADI(A, 128)
        COMPUTE(B, fcb, 1*64)   LOADI(B, 192)
        COMPUTE(A, fcb, 2*64)   LOADI(A, 256)
        COMPUTE(B, fcb, 3*64)   LOADI(B, 320)
        COMPUTE(A, fcb, 4*64)   LOADI(A, i6)
        COMPUTE(B, fcb, 5*64)
        COMPUTE(A, fcb6, 0)

        #pragma unroll
        for (int off = 32; off > 0; off >>= 1) {
            acc0 += __shfl_xor(acc0, off);
            acc1 += __shfl_xor(acc1, off);
            acc2 += __shfl_xor(acc2, off);
            acc3 += __shfl_xor(acc3, off);
        }
        if (lane == 0) {
            partials[g][hc][grp][0] = acc0; partials[g][hc][grp][1] = acc1;
            partials[g][hc][grp][2] = acc2; partials[g][hc][grp][3] = acc3;
        }
    }
    #undef COMPUTE
    #undef LOADI
    #undef SETPTRS

    __syncthreads();

    if (tid < 32) {
        const int g = tid >> 4, idx = tid & 15;
        const int gr = idx >> 2, j = idx & 3;
        const int b = bq + 16 * g + 4 * gr + j;
        if (b < nB)
            out[b] = partials[g][0][gr][j] + partials[g][1][gr][j] + fc_b[0];
    }
}

extern "C" void kernel_launch(void* const* d_in, const int* in_sizes, int n_in,
                              void* d_out, int out_size, void* d_ws, size_t ws_size,
                              hipStream_t stream) {
    const float* entity_emb   = (const float*)d_in[0];
    const float* relation_emb = (const float*)d_in[1];
    const float* conv_w       = (const float*)d_in[2];
    const float* conv_b       = (const float*)d_in[3];
    const float* fc_w         = (const float*)d_in[4];
    const float* fc_b         = (const float*)d_in[5];
    const int*   batch_inputs = (const int*)d_in[6];
    float* out = (float*)d_out;

    const int nB = in_sizes[6] / 3;          // 16384
    const int blocks = (nB + 31) / 32;       // 512
    grcnet_pk16i<<<blocks, 512, 0, stream>>>(
        entity_emb, relation_emb, conv_w, conv_b, fc_w, fc_b, batch_inputs, out, nB);
}

// Round 14
// 60.838 us; speedup vs baseline: 1.8911x; 1.7171x over previous
//
#include <hip/hip_runtime.h>

// GrCNetConvOnly: out[b] = sum_{c,d} relu(wa[c]*h+wb[c]*r+wc[c]*t+cb[c]) * fcw[c*D+d] + fcb
// B=16384, D=400, C=50.
// R12 diag: VALUBusy 65%, VGPR=116 -> 4 waves/SIMD, ~35% idle. R13's forced
// waves_per_eu(6,8) spilled (VGPR 40, 116MB scratch writes) -- forced caps below true
// demand are poison. R14 reduces TRUE demand instead:
//   * conv coeffs in SGPRs via readfirstlane (kept from R13, -52 VGPR)
//   * row pointers wave-uniform SGPR bases + shared per-lane voffset (saddr loads,
//     -22 VGPR + fewer address ops)
//   * waves_per_eu(4,6): min=4 caps at 128 (no spill at ~80 demand); if count <=85
//     hardware reaches 6 waves/SIMD (LDS allows 3 blocks/CU).

typedef _Float16 h2 __attribute__((ext_vector_type(2)));
typedef _Float16 h8 __attribute__((ext_vector_type(8)));

constexpr int D    = 400;
constexpr int CP   = 25;     // real channel pairs
constexpr int DPAD = 404;    // 4 zeroed pad entries per row: inactive lanes read 0

static __device__ __forceinline__ float dot2acc(h2 a, h2 b, float c) {
#if __has_builtin(__builtin_amdgcn_fdot2)
    return __builtin_amdgcn_fdot2(a, b, c, false);
#else
    h2 p = a * b; return c + (float)p[0] + (float)p[1];
#endif
}
static __device__ __forceinline__ h2 dup(float v) {
    _Float16 x = (_Float16)v; h2 r; r[0] = x; r[1] = x; return r;
}
static __device__ __forceinline__ h2 s2h(unsigned u) {
    return __builtin_bit_cast(h2, u);
}

__global__ __attribute__((amdgpu_flat_work_group_size(512, 512), amdgpu_waves_per_eu(4, 6)))
void grcnet_pk16j(
    const float* __restrict__ entity_emb,
    const float* __restrict__ relation_emb,
    const float* __restrict__ conv_w,       // (C,1,1,3)
    const float* __restrict__ conv_b,       // (C)
    const float* __restrict__ fc_w,         // (C*D) c-major
    const float* __restrict__ fc_b,         // (1)
    const int*   __restrict__ batch_inputs, // (B,3)
    float* __restrict__ out,                // (B)
    int nB)
{
    __shared__ h2    fc_lds[CP + 1][DPAD];  // 42016 B; row 25 = zeros (dummy cp)
    __shared__ h2    conv_lds[CP + 1][4];   // row 25 mirrors row 24 (harmless)
    __shared__ float partials[2][2][4][4];  // [g][hc][grp][b]

    const int tid  = threadIdx.x;
    const int lane = tid & 63;
    const int wv   = tid >> 6;              // 0..7
    const int grp  = wv >> 1;               // b-group 0..3
    const int hc   = wv & 1;                // cp-half 0..1
    const int bq   = blockIdx.x * 32;       // 32 b per block
    if (bq >= nB) return;

    // wave-uniform row bases (SGPRs); per-lane offset supplied at each load
    const float *q0h, *q0r, *q0t, *q1h, *q1r, *q1t;
    const float *q2h, *q2r, *q2t, *q3h, *q3r, *q3t;

    #define SETPTRS(B0)                                                           \
    {                                                                             \
        const int bbase = __builtin_amdgcn_readfirstlane((B0) + 4 * grp);         \
        const int* bi = batch_inputs + 3 * bbase;                                 \
        q0h = entity_emb   + (size_t)bi[0]  * D;                                  \
        q0r = relation_emb + (size_t)bi[1]  * D;                                  \
        q0t = entity_emb   + (size_t)bi[2]  * D;                                  \
        q1h = entity_emb   + (size_t)bi[3]  * D;                                  \
        q1r = relation_emb + (size_t)bi[4]  * D;                                  \
        q1t = entity_emb   + (size_t)bi[5]  * D;                                  \
        q2h = entity_emb   + (size_t)bi[6]  * D;                                  \
        q2r = relation_emb + (size_t)bi[7]  * D;                                  \
        q2t = entity_emb   + (size_t)bi[8]  * D;                                  \
        q3h = entity_emb   + (size_t)bi[9]  * D;                                  \
        q3r = relation_emb + (size_t)bi[10] * D;                                  \
        q3t = entity_emb   + (size_t)bi[11] * D;                                  \
    }

    // one shared per-lane index per slot -> saddr-form loads, single voffset
    #define LOADI(S, IDX)                                                         \
    {                                                                             \
        const int _ix = lane + (IDX);                                             \
        f##S##_0h = q0h[_ix]; f##S##_0r = q0r[_ix]; f##S##_0t = q0t[_ix];         \
        f##S##_1h = q1h[_ix]; f##S##_1r = q1r[_ix]; f##S##_1t = q1t[_ix];         \
        f##S##_2h = q2h[_ix]; f##S##_2r = q2r[_ix]; f##S##_2t = q2t[_ix];         \
        f##S##_3h = q3h[_ix]; f##S##_3r = q3r[_ix]; f##S##_3t = q3t[_ix];         \
    }

    float fA_0h, fA_0r, fA_0t, fA_1h, fA_1r, fA_1t;
    float fA_2h, fA_2r, fA_2t, fA_3h, fA_3r, fA_3t;
    float fB_0h, fB_0r, fB_0t, fB_1h, fB_1r, fB_1t;
    float fB_2h, fB_2r, fB_2t, fB_3h, fB_3r, fB_3t;

    const h2 zero2 = (h2)(_Float16)0;

    // ---- stage fc_w: float4 x2 -> one b128 ds_write ----
    for (int k = tid; k < CP * 100; k += 512) {
        const int cp = k / 100;
        const int dq = k - cp * 100;
        const float4 A  = *(const float4*)(fc_w + (2*cp)     * D + 4*dq);
        const float4 Bv = *(const float4*)(fc_w + (2*cp + 1) * D + 4*dq);
        h8 g;
        g[0]=(_Float16)A.x; g[1]=(_Float16)Bv.x;
        g[2]=(_Float16)A.y; g[3]=(_Float16)Bv.y;
        g[4]=(_Float16)A.z; g[5]=(_Float16)Bv.z;
        g[6]=(_Float16)A.w; g[7]=(_Float16)Bv.w;
        *(h8*)&fc_lds[cp][4*dq] = g;
    }
    {
        h2 z; z[0] = (_Float16)0; z[1] = (_Float16)0;
        if (tid < CP * 4) fc_lds[tid >> 2][D + (tid & 3)] = z;      // pad d=400..403
        if (tid >= 64 && tid < 64 + DPAD) fc_lds[CP][tid - 64] = z; // dummy row = 0
    }
    if (tid < CP + 1) {
        const int src = (tid == CP) ? (CP - 1) : tid;
        const int c0 = 2 * src;
        h2 wa, wb, wc, cb;
        wa[0]=(_Float16)conv_w[3*c0+0]; wa[1]=(_Float16)conv_w[3*c0+3];
        wb[0]=(_Float16)conv_w[3*c0+1]; wb[1]=(_Float16)conv_w[3*c0+4];
        wc[0]=(_Float16)conv_w[3*c0+2]; wc[1]=(_Float16)conv_w[3*c0+5];
        cb[0]=(_Float16)conv_b[c0];     cb[1]=(_Float16)conv_b[c0+1];
        conv_lds[tid][0]=wa; conv_lds[tid][1]=wb;
        conv_lds[tid][2]=wc; conv_lds[tid][3]=cb;
    }
    __syncthreads();

    // ---- unified c-range: hc=0 -> cps 0..12; hc=1 -> cps 13..24 + dummy ----
    const int C0 = 13 * hc;
    constexpr int NC = 13;

    // conv coefficients -> SGPRs (wave-uniform; frees ~52 VGPRs)
    unsigned cwa_u[NC], cwb_u[NC], cwc_u[NC], ccb_u[NC];
    #pragma unroll
    for (int j = 0; j < NC; ++j) {
        cwa_u[j] = __builtin_amdgcn_readfirstlane(__builtin_bit_cast(unsigned, conv_lds[C0+j][0]));
        cwb_u[j] = __builtin_amdgcn_readfirstlane(__builtin_bit_cast(unsigned, conv_lds[C0+j][1]));
        cwc_u[j] = __builtin_amdgcn_readfirstlane(__builtin_bit_cast(unsigned, conv_lds[C0+j][2]));
        ccb_u[j] = __builtin_amdgcn_readfirstlane(__builtin_bit_cast(unsigned, conv_lds[C0+j][3]));
    }

    const int  d6 = lane + 384;
    const bool a6 = (d6 < D);
    const int  i6 = a6 ? 384 : -lane;        // lane + i6 == clamped d
    const h2* fcb  = &fc_lds[0][0] + C0 * DPAD + lane;
    const h2* fcb6 = &fc_lds[0][0] + C0 * DPAD + (a6 ? d6 : D);

    #define COMPUTE(S, FB, FIDX0)                                                 \
    {                                                                             \
        const h2 H0=dup(f##S##_0h), R0=dup(f##S##_0r), T0=dup(f##S##_0t);         \
        const h2 H1=dup(f##S##_1h), R1=dup(f##S##_1r), T1=dup(f##S##_1t);         \
        const h2 H2=dup(f##S##_2h), R2=dup(f##S##_2r), T2=dup(f##S##_2t);         \
        const h2 H3=dup(f##S##_3h), R3=dup(f##S##_3r), T3=dup(f##S##_3t);         \
        _Pragma("unroll")                                                         \
        for (int j = 0; j < NC; ++j) {                                            \
            const h2 wa = s2h(cwa_u[j]), wb = s2h(cwb_u[j]);                      \
            const h2 wc = s2h(cwc_u[j]), cb = s2h(ccb_u[j]);                      \
            const h2 f2 = (FB)[(FIDX0) + j * DPAD];      /* imm offset */         \
            h2 s0 = H0*wa + (R0*wb + (T0*wc + cb));                               \
            h2 s1 = H1*wa + (R1*wb + (T1*wc + cb));                               \
            h2 s2 = H2*wa + (R2*wb + (T2*wc + cb));                               \
            h2 s3 = H3*wa + (R3*wb + (T3*wc + cb));                               \
            s0 = __builtin_elementwise_max(s0, zero2);                            \
            s1 = __builtin_elementwise_max(s1, zero2);                            \
            s2 = __builtin_elementwise_max(s2, zero2);                            \
            s3 = __builtin_elementwise_max(s3, zero2);                            \
            acc0 = dot2acc(s0, f2, acc0);                                         \
            acc1 = dot2acc(s1, f2, acc1);                                         \
            acc2 = dot2acc(s2, f2, acc2);                                         \
            acc3 = dot2acc(s3, f2, acc3);                                         \
        }                                                                         \
    }

    #pragma unroll 1
    for (int g = 0; g < 2; ++g) {
        const int b0 = bq + 16 * g;
        SETPTRS(b0)
        LOADI(A, 0)
        LOADI(B, 64)
        float acc0 = 0.f, acc1 = 0.f, acc2 = 0.f, acc3 = 0.f;

        COMPUTE(A, fcb, 0*64)   LOADI(A, 128)
        COMPUTE(B, fcb, 1*64)   LOADI(B, 192)
        COMPUTE(A, fcb, 2*64)   LOADI(A, 256)
        COMPUTE(B, fcb, 3*64)   LOADI(B, 320)
        COMPUTE(A, fcb, 4*64)   LOADI(A, i6)
        COMPUTE(B, fcb, 5*64)
        COMPUTE(A, fcb6, 0)

        #pragma unroll
        for (int off = 32; off > 0; off >>= 1) {
            acc0 += __shfl_xor(acc0, off);
            acc1 += __shfl_xor(acc1, off);
            acc2 += __shfl_xor(acc2, off);
            acc3 += __shfl_xor(acc3, off);
        }
        if (lane == 0) {
            partials[g][hc][grp][0] = acc0; partials[g][hc][grp][1] = acc1;
            partials[g][hc][grp][2] = acc2; partials[g][hc][grp][3] = acc3;
        }
    }
    #undef COMPUTE
    #undef LOADI
    #undef SETPTRS

    __syncthreads();

    if (tid < 32) {
        const int g = tid >> 4, idx = tid & 15;
        const int gr = idx >> 2, j = idx & 3;
        const int b = bq + 16 * g + 4 * gr + j;
        if (b < nB)
            out[b] = partials[g][0][gr][j] + partials[g][1][gr][j] + fc_b[0];
    }
}

extern "C" void kernel_launch(void* const* d_in, const int* in_sizes, int n_in,
                              void* d_out, int out_size, void* d_ws, size_t ws_size,
                              hipStream_t stream) {
    const float* entity_emb   = (const float*)d_in[0];
    const float* relation_emb = (const float*)d_in[1];
    const float* conv_w       = (const float*)d_in[2];
    const float* conv_b       = (const float*)d_in[3];
    const float* fc_w         = (const float*)d_in[4];
    const float* fc_b         = (const float*)d_in[5];
    const int*   batch_inputs = (const int*)d_in[6];
    float* out = (float*)d_out;

    const int nB = in_sizes[6] / 3;          // 16384
    const int blocks = (nB + 31) / 32;       // 512
    grcnet_pk16j<<<blocks, 512, 0, stream>>>(
        entity_emb, relation_emb, conv_w, conv_b, fc_w, fc_b, batch_inputs, out, nB);
}